// Round 1
// baseline (184.912 us; speedup 1.0000x reference)
//
#include <hip/hip_runtime.h>

// AdaptedGaussianConditional: v = inputs - means; nearest-codebook symbol via
// exact lower_bound semantics (tie -> lower index); dequant = codebook[sym] + means.
// Outputs concatenated: [dequant fp32 N | symbols-as-f32 N].
//
// R1: replace per-element 8-step LDS binary search (8-deep dependent chain,
// bank-pathological tree addresses -> 207 conflict cy/wave) with a 2048-bucket
// direct LUT. Uniform buckets (guard-banded +-1 bucket vs fp rounding) resolve
// with 3 independent b32 LDS reads; non-uniform buckets (~31%) fall back to a
// short exact corrective scan from a stored guaranteed lower-bound start.

#define LVL 256
#define NB  2048          // LUT buckets
#define MAINBLOCKS 2048   // grid-stride: amortize 25KB LDS staging over 24 elem/thread

// ---------------- build kernel: writes LUT into workspace ----------------
// ws layout (floats): [0,NB): left | [NB,2NB): right | [2NB,3NB): code (int bits)
// code >= 0 : uniform bucket, code = sym (left=uv[sym], right=uv[sym+1])
// code <  0 : fallback, start = -code-1 is a lower bound on lower_bound(v)
//             for every v that can be assigned to this bucket (incl. +-1 slop)
__global__ __launch_bounds__(256) void agc_build_lut(
    const float* __restrict__ uv, float* __restrict__ ws)
{
    __shared__ float s_uv[LVL];
    if (threadIdx.x < LVL) s_uv[threadIdx.x] = uv[threadIdx.x];
    __syncthreads();

    int b = blockIdx.x * blockDim.x + threadIdx.x;
    if (b >= NB) return;

    float lo    = s_uv[0];
    float width = (s_uv[LVL - 1] - lo) / (float)NB;

    // guard window [edge(b-1), edge(b+2)); buckets 0 / NB-1 own the clamped tails
    float eL = (b == 0)      ? -__builtin_inff() : lo + (float)(b - 1) * width;
    float eU = (b == NB - 1) ?  __builtin_inff() : lo + (float)(b + 2) * width;

    int A, Bc;
    {
        int l = 0, h = LVL;
        #pragma unroll
        for (int s = 0; s < 8; ++s) {
            int m = (l + h) >> 1;
            bool r = (s_uv[m] < eL);
            l = r ? (m + 1) : l;
            h = r ? h : m;
        }
        A = l;                       // #{uv < eL}
        l = 0; h = LVL;
        #pragma unroll
        for (int s = 0; s < 8; ++s) {
            int m = (l + h) >> 1;
            bool r = (s_uv[m] < eU);
            l = r ? (m + 1) : l;
            h = r ? h : m;
        }
        Bc = l;                      // #{uv < eU}
    }
    int cA = min(max(A, 1), LVL - 1);
    int cB = min(max(Bc, 1), LVL - 1);

    float* lutL = ws;
    float* lutR = ws + NB;
    int*   lutS = reinterpret_cast<int*>(ws + 2 * NB);

    if (cA == cB) {
        // clipped lower_bound is constant over the whole guard window
        lutL[b] = s_uv[cA - 1];
        lutR[b] = s_uv[cA];
        lutS[b] = cA - 1;
    } else {
        lutL[b] = 0.0f;
        lutR[b] = 0.0f;
        lutS[b] = -(A + 1);          // fallback: start index A in [0,256]
    }
}

// ---------------- main kernel ----------------
__global__ __launch_bounds__(256) void agc_quant_lut(
    const float* __restrict__ inputs,
    const float* __restrict__ means,
    const float* __restrict__ uv,
    const float* __restrict__ ws,
    float* __restrict__ out_deq,
    float* __restrict__ out_sym,
    int n4, int n, int stride)
{
    __shared__ float s_uv[LVL];
    __shared__ float s_L[NB];
    __shared__ float s_R[NB];
    __shared__ int   s_S[NB];

    s_uv[threadIdx.x] = uv[threadIdx.x];          // blockDim == 256
    {
        const float4* wL = reinterpret_cast<const float4*>(ws);
        const float4* wR = reinterpret_cast<const float4*>(ws + NB);
        const int4*   wS = reinterpret_cast<const int4*>(ws + 2 * NB);
        #pragma unroll
        for (int t = 0; t < NB / 4 / 256; ++t) {  // 2 iters
            int j = t * 256 + threadIdx.x;
            reinterpret_cast<float4*>(s_L)[j] = wL[j];
            reinterpret_cast<float4*>(s_R)[j] = wR[j];
            reinterpret_cast<int4*>(s_S)[j]   = wS[j];
        }
    }
    __syncthreads();

    const float lo    = s_uv[0];
    const float scale = (float)NB / (s_uv[LVL - 1] - lo);

    for (int i = blockIdx.x * blockDim.x + threadIdx.x; i < n4; i += stride) {
        float4 in = reinterpret_cast<const float4*>(inputs)[i];
        float4 mn = reinterpret_cast<const float4*>(means)[i];

        float vs[4] = {in.x - mn.x, in.y - mn.y, in.z - mn.z, in.w - mn.w};
        float ms[4] = {mn.x, mn.y, mn.z, mn.w};
        float dq[4], sy[4];

        #pragma unroll
        for (int k = 0; k < 4; ++k) {
            float v = vs[k];
            int b = (int)floorf((v - lo) * scale);
            b = min(max(b, 0), NB - 1);

            float left  = s_L[b];
            float right = s_R[b];
            int   code  = s_S[b];
            int   base  = code;

            if (code < 0) {
                // exact corrective scan: start is a guaranteed lower bound,
                // indices below it satisfy uv[i] < v, so result is the true
                // lower_bound regardless of bucket rounding slop.
                int s = -code - 1;
                while (s < LVL && s_uv[s] < v) ++s;
                int idx = min(max(s, 1), LVL - 1);
                left  = s_uv[idx - 1];
                right = s_uv[idx];
                base  = idx - 1;
            }

            bool tl = (fabsf(v - left) <= fabsf(v - right));   // identical to reference
            sy[k] = (float)(tl ? base : base + 1);
            dq[k] = (tl ? left : right) + ms[k];
        }

        reinterpret_cast<float4*>(out_deq)[i] = make_float4(dq[0], dq[1], dq[2], dq[3]);
        reinterpret_cast<float4*>(out_sym)[i] = make_float4(sy[0], sy[1], sy[2], sy[3]);
    }

    // tail (n % 4 != 0) — n here is 12.58M, rem = 0
    if (blockIdx.x == 0 && threadIdx.x == 0) {
        for (int j = n4 * 4; j < n; ++j) {
            float m = means[j];
            float v = inputs[j] - m;
            int l = 0, h = LVL;
            for (int s = 0; s < 8; ++s) {
                int mm = (l + h) >> 1;
                bool r = (s_uv[mm] < v);
                l = r ? (mm + 1) : l;
                h = r ? h : mm;
            }
            int idx = min(max(l, 1), LVL - 1);
            float left = s_uv[idx - 1], right = s_uv[idx];
            bool tl = fabsf(v - left) <= fabsf(v - right);
            out_deq[j] = (tl ? left : right) + m;
            out_sym[j] = (float)(tl ? idx - 1 : idx);
        }
    }
}

// ---------------- safety fallback (no/short workspace): previous kernel ----------------
__global__ __launch_bounds__(256) void agc_quant_fallback(
    const float* __restrict__ inputs,
    const float* __restrict__ means,
    const float* __restrict__ uv,
    float* __restrict__ out_deq,
    float* __restrict__ out_sym,
    int n4, int n)
{
    __shared__ float s_uv[LVL];
    s_uv[threadIdx.x] = uv[threadIdx.x];
    __syncthreads();

    int i = blockIdx.x * blockDim.x + threadIdx.x;
    if (i < n4) {
        float4 in = reinterpret_cast<const float4*>(inputs)[i];
        float4 mn = reinterpret_cast<const float4*>(means)[i];
        float vs[4] = {in.x - mn.x, in.y - mn.y, in.z - mn.z, in.w - mn.w};
        float ms[4] = {mn.x, mn.y, mn.z, mn.w};
        float dq[4], sy[4];
        #pragma unroll
        for (int k = 0; k < 4; ++k) {
            float v = vs[k];
            int lo = 0, hi = LVL;
            #pragma unroll
            for (int s = 0; s < 8; ++s) {
                int mid = (lo + hi) >> 1;
                bool r = (s_uv[mid] < v);
                lo = r ? (mid + 1) : lo;
                hi = r ? hi : mid;
            }
            int idx = min(max(lo, 1), LVL - 1);
            float left = s_uv[idx - 1], right = s_uv[idx];
            bool tl = (fabsf(v - left) <= fabsf(v - right));
            sy[k] = (float)(tl ? idx - 1 : idx);
            dq[k] = (tl ? left : right) + ms[k];
        }
        reinterpret_cast<float4*>(out_deq)[i] = make_float4(dq[0], dq[1], dq[2], dq[3]);
        reinterpret_cast<float4*>(out_sym)[i] = make_float4(sy[0], sy[1], sy[2], sy[3]);
    }
    if (blockIdx.x == 0 && threadIdx.x == 0) {
        for (int j = n4 * 4; j < n; ++j) {
            float m = means[j];
            float v = inputs[j] - m;
            int lo = 0, hi = LVL;
            for (int s = 0; s < 8; ++s) {
                int mid = (lo + hi) >> 1;
                bool r = (s_uv[mid] < v);
                lo = r ? (mid + 1) : lo;
                hi = r ? hi : mid;
            }
            int idx = min(max(lo, 1), LVL - 1);
            float left = s_uv[idx - 1], right = s_uv[idx];
            bool tl = fabsf(v - left) <= fabsf(v - right);
            out_deq[j] = (tl ? left : right) + m;
            out_sym[j] = (float)(tl ? idx - 1 : idx);
        }
    }
}

extern "C" void kernel_launch(void* const* d_in, const int* in_sizes, int n_in,
                              void* d_out, int out_size, void* d_ws, size_t ws_size,
                              hipStream_t stream)
{
    const float* inputs = (const float*)d_in[0];
    const float* means  = (const float*)d_in[1];
    const float* uv     = (const float*)d_in[2];

    int n  = in_sizes[0];        // 12,582,912
    int n4 = n / 4;

    float* out     = (float*)d_out;
    float* out_deq = out;        // first N: dequant
    float* out_sym = out + n;    // second N: symbols (exact float values)

    size_t need = (size_t)NB * 3 * sizeof(float);   // 24 KB
    if (d_ws != nullptr && ws_size >= need) {
        agc_build_lut<<<NB / 256, 256, 0, stream>>>(uv, (float*)d_ws);

        int blocks = (n4 + 255) / 256;
        if (blocks > MAINBLOCKS) blocks = MAINBLOCKS;
        if (blocks < 1)          blocks = 1;
        agc_quant_lut<<<blocks, 256, 0, stream>>>(
            inputs, means, uv, (const float*)d_ws,
            out_deq, out_sym, n4, n, blocks * 256);
    } else {
        int blocks = (n4 + 255) / 256;
        if (blocks < 1) blocks = 1;
        agc_quant_fallback<<<blocks, 256, 0, stream>>>(
            inputs, means, uv, out_deq, out_sym, n4, n);
    }
}